// Round 1
// baseline (795.981 us; speedup 1.0000x reference)
//
#include <hip/hip_runtime.h>
#include <math.h>

#define CCH 64
#define NSP 64

// ---------------------------------------------------------------------------
// Kernel 1: circular 3x3 conv, per-sample kernels, + bias, + identity kernel.
// out[b,co,y,x] = bias[b,co] + sum_{ci,kh,kw} in[b,ci,(y+kh-1)&63,(x+kw-1)&63]
//                  * (K[b,co,ci,kh,kw] + (co==ci && kh==1 && kw==1))
// One block per (b,co). 256 threads; thread t owns row ty=t>>2, cols [16*(t&3), +16).
// Input channel staged in LDS with stride 65 (conflict-free for this mapping).
// ---------------------------------------------------------------------------
__global__ __launch_bounds__(256) void conv_kernel(
    const float* __restrict__ x, const float* __restrict__ K,
    const float* __restrict__ bias, float* __restrict__ out) {
  int bid = blockIdx.x;            // 0..255
  int b = bid >> 6, co = bid & 63;
  __shared__ float w[CCH * 9];
  __shared__ float tile[64 * 65];
  int t = threadIdx.x;

  // stage this (b,co)'s 64x3x3 kernel slice, fusing the identity add
  for (int i = t; i < CCH * 9; i += 256) {
    float v = K[(size_t)((b * 64 + co) * 64) * 9 + i];
    if (i == co * 9 + 4) v += 1.0f;   // identity: ci==co, kh=kw=1
    w[i] = v;
  }

  int ty = t >> 2;                 // 0..63 (output row)
  int tx = t & 3;
  int x0 = tx << 4;                // 16 output cols per thread
  float bval = bias[b * 64 + co];
  float acc[16];
#pragma unroll
  for (int i = 0; i < 16; ++i) acc[i] = bval;

  const float* xb = x + (size_t)(b * 64) * 4096;
  for (int ci = 0; ci < 64; ++ci) {
    __syncthreads();               // protect tile overwrite (and w on first iter)
    const float* xc = xb + (size_t)ci * 4096;
#pragma unroll
    for (int j = 0; j < 16; ++j) {
      int i = t + 256 * j;         // coalesced global read
      tile[(i >> 6) * 65 + (i & 63)] = xc[i];
    }
    __syncthreads();

    float w0 = w[ci * 9 + 0], w1 = w[ci * 9 + 1], w2 = w[ci * 9 + 2];
    float w3 = w[ci * 9 + 3], w4 = w[ci * 9 + 4], w5 = w[ci * 9 + 5];
    float w6 = w[ci * 9 + 6], w7 = w[ci * 9 + 7], w8 = w[ci * 9 + 8];

    int ym = ((ty - 1) & 63) * 65;
    int yc = ty * 65;
    int yp = ((ty + 1) & 63) * 65;
    float in0[18], in1[18], in2[18];
#pragma unroll
    for (int ix = 0; ix < 18; ++ix) {
      int xx = (x0 + ix - 1) & 63;
      in0[ix] = tile[ym + xx];
      in1[ix] = tile[yc + xx];
      in2[ix] = tile[yp + xx];
    }
#pragma unroll
    for (int px = 0; px < 16; ++px) {
      float a = acc[px];
      a = fmaf(w0, in0[px], a); a = fmaf(w1, in0[px + 1], a); a = fmaf(w2, in0[px + 2], a);
      a = fmaf(w3, in1[px], a); a = fmaf(w4, in1[px + 1], a); a = fmaf(w5, in1[px + 2], a);
      a = fmaf(w6, in2[px], a); a = fmaf(w7, in2[px + 1], a); a = fmaf(w8, in2[px + 2], a);
      acc[px] = a;
    }
  }

  float* op = out + (size_t)(b * 64 + co) * 4096 + ty * 64 + x0;
#pragma unroll
  for (int i = 0; i < 16; i += 4) {
    *(float4*)(op + i) = make_float4(acc[i], acc[i + 1], acc[i + 2], acc[i + 3]);
  }
}

// ---------------------------------------------------------------------------
// Kernel 2: per-frequency 64x64 complex LU -> sum of log|pivot|.
// One 64-thread block (1 wave) per (b,u,v); lane r owns row r in registers.
// Conjugate symmetry: only canonical (u,v) processed, weight 2 for pairs.
// Partial pivoting among still-active rows (no physical swap; pivot row is
// broadcast via LDS and retired). All register indices compile-time via
// chunk-of-16 unrolled loops with uniform scalar guards.
// ---------------------------------------------------------------------------
__global__ __launch_bounds__(64, 2) void logdet_kernel(
    const float* __restrict__ K, float* __restrict__ logdet) {
  int u = blockIdx.x >> 6, v = blockIdx.x & 63;
  int b = blockIdx.y;
  int u2 = (64 - u) & 63, v2 = (64 - v) & 63;
  int key = (u << 6) | v, key2 = (u2 << 6) | v2;
  if (key2 < key) return;                    // partner handles it with weight 2
  float weight = (key2 == key) ? 1.0f : 2.0f;

  int r = threadIdx.x;                       // lane == matrix row (co)

  // 9 twiddles e^{-2*pi*i*(u*kh + v*kw)/64}
  float wr[9], wi[9];
#pragma unroll
  for (int t9 = 0; t9 < 9; ++t9) {
    int kh = t9 / 3, kw = t9 % 3;
    float ang = -2.0f * 3.14159265358979323846f * (float)(u * kh + v * kw) / 64.0f;
    float s, c;
    sincosf(ang, &s, &c);
    wr[t9] = c; wi[t9] = s;
  }

  // Build row r of Khat: ar/ai[c] = sum_t K[b,r,c,t] * (wr[t], wi[t]) (+ identity phase on diag)
  float ar[64], ai[64];
  const float* Kp = K + (size_t)((b * 64 + r) * 64) * 9;
#pragma unroll
  for (int c = 0; c < 64; ++c) {
    float re = 0.0f, im = 0.0f;
#pragma unroll
    for (int t9 = 0; t9 < 9; ++t9) {
      float kv = Kp[c * 9 + t9];
      re = fmaf(kv, wr[t9], re);
      im = fmaf(kv, wi[t9], im);
    }
    if (c == r) { re += wr[4]; im += wi[4]; }  // identity kernel: delta at center
    ar[c] = re; ai[c] = im;
  }

  __shared__ float2 Lrow[64];
  float front_re = ar[0], front_im = ai[0];    // current pivot-column entry of my row
  bool active = true;
  float logsum = 0.0f;

  for (int k = 0; k < 64; ++k) {
    float mag = active ? fmaf(front_re, front_re, front_im * front_im) : -1.0f;
    float m = mag;
#pragma unroll
    for (int off = 32; off > 0; off >>= 1) m = fmaxf(m, __shfl_xor(m, off));
    unsigned long long msk = __ballot(mag == m);
    int p = __ffsll(msk) - 1;                  // deterministic pivot lane
    logsum += 0.5f * __logf(m);                // log|pivot|

    if (k == 63) break;

    float piv_re = __shfl(front_re, p);
    float piv_im = __shfl(front_im, p);

    if (r == p) {
      active = false;
#pragma unroll
      for (int ch = 0; ch < 4; ++ch) {
        if (ch * 16 + 15 > k) {                // uniform scalar guard
#pragma unroll
          for (int j = 0; j < 16; ++j) {
            int c = ch * 16 + j;
            Lrow[c] = make_float2(ar[c], ai[c]);
          }
        }
      }
    }
    __syncthreads();

    if (active) {
      float inv = 1.0f / m;                    // m == |piv|^2 (uniform)
      float fre = (front_re * piv_re + front_im * piv_im) * inv;
      float fim = (front_im * piv_re - front_re * piv_im) * inv;
#pragma unroll
      for (int ch = 0; ch < 4; ++ch) {
        if (ch * 16 + 15 > k) {                // uniform scalar guard
#pragma unroll
          for (int j = 0; j < 16; ++j) {
            int c = ch * 16 + j;
            float lr = Lrow[c].x, li = Lrow[c].y;
            float nr = ar[c] - (fre * lr - fim * li);
            float ni = ai[c] - (fre * li + fim * lr);
            ar[c] = nr; ai[c] = ni;
            if (c == k + 1) { front_re = nr; front_im = ni; }  // capture next front
          }
        }
      }
    }
    __syncthreads();                           // WAR: next iter's Lrow write vs this iter's reads
  }

  if (r == 0) atomicAdd(&logdet[b], weight * logsum);
}

// ---------------------------------------------------------------------------
extern "C" void kernel_launch(void* const* d_in, const int* in_sizes, int n_in,
                              void* d_out, int out_size, void* d_ws, size_t ws_size,
                              hipStream_t stream) {
  const float* conv_in = (const float*)d_in[0];   // [4,64,64,64]
  const float* K       = (const float*)d_in[1];   // [4,64,64,3,3]
  const float* bias    = (const float*)d_in[2];   // [4,64,1,1]
  float* out = (float*)d_out;                     // conv_out (1048576) ++ logdet (4)
  float* logdet = out + 1048576;

  hipMemsetAsync(logdet, 0, 4 * sizeof(float), stream);  // d_out is poisoned pre-call
  conv_kernel<<<dim3(256), dim3(256), 0, stream>>>(conv_in, K, bias, out);
  logdet_kernel<<<dim3(4096, 4), dim3(64), 0, stream>>>(K, logdet);
}

// Round 2
// 702.973 us; speedup vs baseline: 1.1323x; 1.1323x over previous
//
#include <hip/hip_runtime.h>
#include <math.h>

#define CCH 64
#define NSP 64

// ---------------------------------------------------------------------------
// Kernel 1: circular 3x3 conv, per-sample kernels, + bias, + identity kernel.
// (unchanged from round 1 — ~<74us, not the bottleneck this round)
// ---------------------------------------------------------------------------
__global__ __launch_bounds__(256) void conv_kernel(
    const float* __restrict__ x, const float* __restrict__ K,
    const float* __restrict__ bias, float* __restrict__ out) {
  int bid = blockIdx.x;            // 0..255
  int b = bid >> 6, co = bid & 63;
  __shared__ float w[CCH * 9];
  __shared__ float tile[64 * 65];
  int t = threadIdx.x;

  for (int i = t; i < CCH * 9; i += 256) {
    float v = K[(size_t)((b * 64 + co) * 64) * 9 + i];
    if (i == co * 9 + 4) v += 1.0f;   // identity: ci==co, kh=kw=1
    w[i] = v;
  }

  int ty = t >> 2;
  int tx = t & 3;
  int x0 = tx << 4;
  float bval = bias[b * 64 + co];
  float acc[16];
#pragma unroll
  for (int i = 0; i < 16; ++i) acc[i] = bval;

  const float* xb = x + (size_t)(b * 64) * 4096;
  for (int ci = 0; ci < 64; ++ci) {
    __syncthreads();
    const float* xc = xb + (size_t)ci * 4096;
#pragma unroll
    for (int j = 0; j < 16; ++j) {
      int i = t + 256 * j;
      tile[(i >> 6) * 65 + (i & 63)] = xc[i];
    }
    __syncthreads();

    float w0 = w[ci * 9 + 0], w1 = w[ci * 9 + 1], w2 = w[ci * 9 + 2];
    float w3 = w[ci * 9 + 3], w4 = w[ci * 9 + 4], w5 = w[ci * 9 + 5];
    float w6 = w[ci * 9 + 6], w7 = w[ci * 9 + 7], w8 = w[ci * 9 + 8];

    int ym = ((ty - 1) & 63) * 65;
    int yc = ty * 65;
    int yp = ((ty + 1) & 63) * 65;
    float in0[18], in1[18], in2[18];
#pragma unroll
    for (int ix = 0; ix < 18; ++ix) {
      int xx = (x0 + ix - 1) & 63;
      in0[ix] = tile[ym + xx];
      in1[ix] = tile[yc + xx];
      in2[ix] = tile[yp + xx];
    }
#pragma unroll
    for (int px = 0; px < 16; ++px) {
      float a = acc[px];
      a = fmaf(w0, in0[px], a); a = fmaf(w1, in0[px + 1], a); a = fmaf(w2, in0[px + 2], a);
      a = fmaf(w3, in1[px], a); a = fmaf(w4, in1[px + 1], a); a = fmaf(w5, in1[px + 2], a);
      a = fmaf(w6, in2[px], a); a = fmaf(w7, in2[px + 1], a); a = fmaf(w8, in2[px + 2], a);
      acc[px] = a;
    }
  }

  float* op = out + (size_t)(b * 64 + co) * 4096 + ty * 64 + x0;
#pragma unroll
  for (int i = 0; i < 16; i += 4) {
    *(float4*)(op + i) = make_float4(acc[i], acc[i + 1], acc[i + 2], acc[i + 3]);
  }
}

// ---------------------------------------------------------------------------
// Kernel 2: per-frequency 64x64 complex LU -> sum log|pivot|.
// One wave per canonical (b,u,v); lane r owns row r, COLUMN-COMPACTED:
// at step k the remaining columns live at indices 0..63-k with the pivot
// column always at index 0. All register indices are compile-time constants
// independent of k -> no spill, no per-element front-capture cndmask.
// Retired/pivot lanes keep running with multiplier f=0 (branch-free update).
// Pivot row broadcast: packed float4 LDS writes + broadcast float4 reads.
// ---------------------------------------------------------------------------
__global__ __launch_bounds__(64, 2) void logdet_kernel(
    const float* __restrict__ K, float* __restrict__ logdet) {
  int u = blockIdx.x >> 6, v = blockIdx.x & 63;
  int b = blockIdx.y;
  int key = blockIdx.x;
  int key2 = (((64 - u) & 63) << 6) | ((64 - v) & 63);
  if (key2 < key) return;                    // conjugate partner, weight 2 below
  float weight = (key2 == key) ? 1.0f : 2.0f;

  int r = threadIdx.x;                       // lane == matrix row

  // twiddles w[kh*3+kw] = e^{-2*pi*i*(u*kh+v*kw)/64} via complex power products
  float Ar[3], Ai[3], Br[3], Bi[3];
  {
    const float k2pi = -6.283185307179586f / 64.0f;
    float su, cu, sv, cv;
    __sincosf(k2pi * (float)u, &su, &cu);
    __sincosf(k2pi * (float)v, &sv, &cv);
    Ar[0] = 1.0f; Ai[0] = 0.0f; Ar[1] = cu; Ai[1] = su;
    Ar[2] = cu * cu - su * su; Ai[2] = 2.0f * cu * su;
    Br[0] = 1.0f; Bi[0] = 0.0f; Br[1] = cv; Bi[1] = sv;
    Br[2] = cv * cv - sv * sv; Bi[2] = 2.0f * cv * sv;
  }
  float wr[9], wi[9];
#pragma unroll
  for (int kh = 0; kh < 3; ++kh)
#pragma unroll
    for (int kw = 0; kw < 3; ++kw) {
      wr[kh * 3 + kw] = Ar[kh] * Br[kw] - Ai[kh] * Bi[kw];
      wi[kh * 3 + kw] = Ar[kh] * Bi[kw] + Ai[kh] * Br[kw];
    }

  // Build row r of Khat with aligned float4 loads (row = 576 floats, 16B-aligned)
  float ar[65], ai[65];
  const float4* Kp4 = (const float4*)(K + (size_t)(b * 64 + r) * 576);
#pragma unroll
  for (int g = 0; g < 16; ++g) {             // 16 groups x 4 columns (36 floats)
    float f[36];
#pragma unroll
    for (int q = 0; q < 9; ++q) {
      float4 vv = Kp4[g * 9 + q];
      f[q * 4 + 0] = vv.x; f[q * 4 + 1] = vv.y; f[q * 4 + 2] = vv.z; f[q * 4 + 3] = vv.w;
    }
#pragma unroll
    for (int cc = 0; cc < 4; ++cc) {
      int c = g * 4 + cc;
      float re = 0.0f, im = 0.0f;
#pragma unroll
      for (int t9 = 0; t9 < 9; ++t9) {
        float kv = f[cc * 9 + t9];
        re = fmaf(kv, wr[t9], re);
        im = fmaf(kv, wi[t9], im);
      }
      if (c == r) { re += wr[4]; im += wi[4]; }  // identity: delta at center tap
      ar[c] = re; ai[c] = im;
    }
  }
  ar[64] = 0.0f; ai[64] = 0.0f;              // pad slot read by chunk 3

  __shared__ float Lr[64], Li[64];
  bool active = true;
  float logsum = 0.0f;

  for (int k = 0; k < 64; ++k) {
    float mag = active ? fmaf(ar[0], ar[0], ai[0] * ai[0]) : -1.0f;
    float m = mag;
#pragma unroll
    for (int off = 32; off > 0; off >>= 1) m = fmaxf(m, __shfl_xor(m, off));
    logsum += 0.5f * __logf(m);              // log|pivot|
    if (k == 63) break;

    unsigned long long msk = __ballot(mag == m);
    int p = __ffsll(msk) - 1;                // deterministic pivot lane
    float pr = __shfl(ar[0], p);
    float pi = __shfl(ai[0], p);
    int rem = 63 - k;                        // remaining columns (indices 1..rem)

    if (r == p) {                            // broadcast pivot row (packed)
      active = false;
#pragma unroll
      for (int ch = 0; ch < 4; ++ch) {
        if (ch * 16 < rem) {
#pragma unroll
          for (int j = 0; j < 4; ++j) {
            int c = ch * 16 + j * 4 + 1;
            ((float4*)Lr)[ch * 4 + j] = make_float4(ar[c], ar[c + 1], ar[c + 2], ar[c + 3]);
            ((float4*)Li)[ch * 4 + j] = make_float4(ai[c], ai[c + 1], ai[c + 2], ai[c + 3]);
          }
        }
      }
    }
    __syncthreads();

    // multiplier f = front * conj(piv) / |piv|^2 ; 0 for pivot/retired lanes
    float inv = 1.0f / m;                    // m == |piv|^2 (wave-uniform)
    float fre = (ar[0] * pr + ai[0] * pi) * inv;
    float fim = (ai[0] * pr - ar[0] * pi) * inv;
    bool use = active && (r != p);
    fre = use ? fre : 0.0f;
    fim = use ? fim : 0.0f;

    // rank-1 update with compaction shift: ar[c-1] = ar[c] - f*L[c]
#pragma unroll
    for (int ch = 0; ch < 4; ++ch) {
      if (ch * 16 < rem) {
#pragma unroll
        for (int j = 0; j < 4; ++j) {
          float4 l4r = ((float4*)Lr)[ch * 4 + j];
          float4 l4i = ((float4*)Li)[ch * 4 + j];
          float lrA[4] = {l4r.x, l4r.y, l4r.z, l4r.w};
          float liA[4] = {l4i.x, l4i.y, l4i.z, l4i.w};
          int c0 = ch * 16 + j * 4 + 1;
#pragma unroll
          for (int e = 0; e < 4; ++e) {
            int c = c0 + e;
            float nr = fmaf(fim, liA[e], fmaf(-fre, lrA[e], ar[c]));
            float ni = fmaf(-fim, lrA[e], fmaf(-fre, liA[e], ai[c]));
            ar[c - 1] = nr;
            ai[c - 1] = ni;
          }
        }
      }
    }
    __syncthreads();                         // WAR vs next iteration's Lrow write
  }

  if (r == 0) atomicAdd(&logdet[b], weight * logsum);
}

// ---------------------------------------------------------------------------
extern "C" void kernel_launch(void* const* d_in, const int* in_sizes, int n_in,
                              void* d_out, int out_size, void* d_ws, size_t ws_size,
                              hipStream_t stream) {
  const float* conv_in = (const float*)d_in[0];   // [4,64,64,64]
  const float* K       = (const float*)d_in[1];   // [4,64,64,3,3]
  const float* bias    = (const float*)d_in[2];   // [4,64,1,1]
  float* out = (float*)d_out;                     // conv_out (1048576) ++ logdet (4)
  float* logdet = out + 1048576;

  hipMemsetAsync(logdet, 0, 4 * sizeof(float), stream);
  conv_kernel<<<dim3(256), dim3(256), 0, stream>>>(conv_in, K, bias, out);
  logdet_kernel<<<dim3(4096, 4), dim3(64), 0, stream>>>(K, logdet);
}